// Round 1
// baseline (28.721 us; speedup 1.0000x reference)
//
#include <hip/hip_runtime.h>
#include <hip/hip_bf16.h>

#define BS 32
#define NQ 300
#define NC 92
#define NT 50
#define Q_TOT (BS * NQ)   // 9600
#define T_TOT (BS * NT)   // 1600
#define QPB 8             // q-rows per block (9600 = 1200 * 8)
#define TPB 320           // threads per block = targets per block (1600 = 5 * 320)

// Kernel 1: per-query softmax stats (rowmax, 1/sum(exp)) — one wave64 per row.
__global__ __launch_bounds__(256) void softmax_stats_kernel(
    const float* __restrict__ logits,   // [Q_TOT, NC]
    float2* __restrict__ stats)         // [Q_TOT] (m, inv_sum)
{
    const int row  = blockIdx.x * 4 + (threadIdx.x >> 6);
    const int lane = threadIdx.x & 63;
    if (row >= Q_TOT) return;

    const float* rp = logits + (size_t)row * NC;
    float x0 = (lane < NC)      ? rp[lane]      : -INFINITY;
    float x1 = (lane + 64 < NC) ? rp[lane + 64] : -INFINITY;

    float m = fmaxf(x0, x1);
    #pragma unroll
    for (int off = 1; off < 64; off <<= 1)
        m = fmaxf(m, __shfl_xor(m, off));

    // expf(-inf - m) == 0, so invalid lanes contribute nothing.
    float s = __expf(x0 - m) + __expf(x1 - m);
    #pragma unroll
    for (int off = 1; off < 64; off <<= 1)
        s += __shfl_xor(s, off);

    if (lane == 0)
        stats[row] = make_float2(m, 1.0f / s);
}

// Kernel 2: fused cost matrix. Each thread: one target t, loops over QPB query rows.
__global__ __launch_bounds__(TPB) void cost_kernel(
    const float* __restrict__ pred_logits,  // [Q_TOT, NC]
    const float* __restrict__ pred_boxes,   // [Q_TOT, 4] cxcywh
    const int*   __restrict__ tgt_labels,   // [T_TOT]
    const float* __restrict__ tgt_boxes,    // [T_TOT, 4] cxcywh
    const float2* __restrict__ stats,       // [Q_TOT]
    float* __restrict__ out)                // [Q_TOT, T_TOT]
{
    const int t  = blockIdx.x * TPB + threadIdx.x;
    const int q0 = blockIdx.y * QPB;

    // Target-side data: registers for the whole q-loop.
    const float4 tb = *reinterpret_cast<const float4*>(tgt_boxes + 4 * t); // cx cy w h
    const float tx0 = tb.x - 0.5f * tb.z, ty0 = tb.y - 0.5f * tb.w;
    const float tx1 = tb.x + 0.5f * tb.z, ty1 = tb.y + 0.5f * tb.w;
    const float tarea = tb.z * tb.w;
    const int lbl = tgt_labels[t];

    #pragma unroll
    for (int i = 0; i < QPB; ++i) {
        const int q = q0 + i;
        const float4 qb = *reinterpret_cast<const float4*>(pred_boxes + 4 * q);
        const float2 st = stats[q];
        const float logit = pred_logits[(size_t)q * NC + lbl];
        const float prob  = __expf(logit - st.x) * st.y;   // softmax prob at target class

        // L1 cost in cxcywh space
        const float l1 = fabsf(qb.x - tb.x) + fabsf(qb.y - tb.y)
                       + fabsf(qb.z - tb.z) + fabsf(qb.w - tb.w);

        // GIoU in xyxy space
        const float qx0 = qb.x - 0.5f * qb.z, qy0 = qb.y - 0.5f * qb.w;
        const float qx1 = qb.x + 0.5f * qb.z, qy1 = qb.y + 0.5f * qb.w;
        const float qarea = qb.z * qb.w;

        const float ix0 = fmaxf(qx0, tx0), iy0 = fmaxf(qy0, ty0);
        const float ix1 = fminf(qx1, tx1), iy1 = fminf(qy1, ty1);
        const float iw = fmaxf(ix1 - ix0, 0.0f), ih = fmaxf(iy1 - iy0, 0.0f);
        const float inter = iw * ih;
        const float uni   = qarea + tarea - inter;
        const float iou   = inter * __builtin_amdgcn_rcpf(uni);

        const float ex0 = fminf(qx0, tx0), ey0 = fminf(qy0, ty0);
        const float ex1 = fmaxf(qx1, tx1), ey1 = fmaxf(qy1, ty1);
        const float ew = fmaxf(ex1 - ex0, 0.0f), eh = fmaxf(ey1 - ey0, 0.0f);
        const float earea = ew * eh;
        const float giou  = iou - (earea - uni) * __builtin_amdgcn_rcpf(earea);

        // C = 1*l1 + 1*(-prob) + 1*(-giou)
        out[(size_t)q * T_TOT + t] = l1 - prob - giou;
    }
}

extern "C" void kernel_launch(void* const* d_in, const int* in_sizes, int n_in,
                              void* d_out, int out_size, void* d_ws, size_t ws_size,
                              hipStream_t stream) {
    const float* pred_logits = (const float*)d_in[0]; // [32,300,92]
    const float* pred_boxes  = (const float*)d_in[1]; // [32,300,4]
    const int*   tgt_labels  = (const int*)d_in[2];   // [32,50]
    const float* tgt_boxes   = (const float*)d_in[3]; // [32,50,4]
    float* out = (float*)d_out;                       // [32,300,1600]

    float2* stats = (float2*)d_ws;                    // [9600] (m, inv_sum) = 76.8 KB

    softmax_stats_kernel<<<Q_TOT / 4, 256, 0, stream>>>(pred_logits, stats);

    dim3 grid(T_TOT / TPB, Q_TOT / QPB);              // (5, 1200)
    cost_kernel<<<grid, TPB, 0, stream>>>(pred_logits, pred_boxes, tgt_labels,
                                          tgt_boxes, stats, out);
}